// Round 5
// baseline (172.379 us; speedup 1.0000x reference)
//
#include <hip/hip_runtime.h>

// LocalNonLocal2D v4: single fused kernel, 8 waves/block, reg-staged halo.
//   Wave wv owns channels [16wv, 16wv+16): 4 groups of 4ch.
//   Staging per group: 16 coalesced global loads (plane-major row segments,
//   consecutive lanes -> consecutive addresses), in-register transpose, then
//   4x ds_write_b128 (lane = halo entry, 4 planes = 16B). Single halo buffer
//   per wave (same-wave LDS ordering makes write->read->overwrite safe).
//   No inline asm: compiler-tracked loads give counted vmcnt waits; there are
//   no barriers inside the staging loops to force vmcnt(0) drains.
//   Cross-wave w[49] reduce via LDS atomics into wred[64][53] (stride 53).

namespace {

constexpr int CN = 4, CC = 128, HT = 80, WD = 80;
constexpr int KK = 7, K2 = 49, PD = 3;
constexpr int TW = 16, TH = 4;      // pixel tile (64 px, lane = pixel)
constexpr int HW_ = TW + 6;         // 22 halo cols
constexpr int HENT = 22 * 10;       // 220 halo entries (float4 each)
constexpr int PLANE = HT * WD;      // 6400
constexpr int GSTRIDE = 4 * PLANE;  // one 4-channel group step
constexpr int OUT_ELEMS = CN * CC * PLANE;
constexpr int NW = 8;               // waves per block
constexpr int GPW = 4;              // 4 groups x 4ch = 16 ch per wave
constexpr int WR = 53;              // wred row stride (odd -> 2-way max)

__global__ __launch_bounds__(512) void lnl2d_v4(const float* __restrict__ x,
                                                const float* __restrict__ feat,
                                                float* __restrict__ dout) {
  __shared__ float4 halo[NW][256];  // 32768 B (one buffer per wave)
  __shared__ float wred[64][WR];    // 13568 B
  __shared__ float inv[64];         // 256 B

  const int tid  = (int)threadIdx.x;
  const int wv   = tid >> 6;
  const int lane = tid & 63;
  const int tx = lane & (TW - 1), ty = lane >> 4;
  const int bx = (int)blockIdx.x, by = (int)blockIdx.y, n = (int)blockIdx.z;
  const int h = by * TH + ty, w = bx * TW + tx;

  const float* xw = x + (size_t)n * CC * PLANE + (size_t)wv * 16 * PLANE;
  const float* fw = feat + (size_t)n * CC * PLANE + (size_t)wv * 16 * PLANE;
  float* out = dout;
  float* pw  = dout + OUT_ELEMS;

  // Per-lane pixel offset for each of the 4 entry-chunks (clamped into image;
  // OOB taps zeroed post-accumulation). Entry e = c*64+lane, (r,cl)=e/22,e%22.
  int off4[4];
  int eclamp[4];
#pragma unroll
  for (int c = 0; c < 4; ++c) {
    int e = c * 64 + lane;
    if (e > HENT - 1) e = HENT - 1;  // dup lanes: same addr, same value -> benign
    eclamp[c] = e;
    const int r = e / HW_, cl = e - r * HW_;
    int gh = by * TH - PD + r;
    gh = gh < 0 ? 0 : (gh > HT - 1 ? HT - 1 : gh);
    int gw = bx * TW - PD + cl;
    gw = gw < 0 ? 0 : (gw > WD - 1 ? WD - 1 : gw);
    off4[c] = gh * WD + gw;
  }

  // init wred; barrier before any atomics land
#pragma unroll
  for (int i = 0; i < (64 * WR + 511) / 512; ++i) {
    const int idx = i * 512 + tid;
    if (idx < 64 * WR) ((float*)wred)[idx] = 0.f;
  }
  __syncthreads();

  // 16 coalesced loads: plane p, chunk c -> lanes read consecutive pixels
  auto ldg = [&](const float* gbase, float (&s)[16]) {
#pragma unroll
    for (int p = 0; p < 4; ++p) {
      const float* bp = gbase + p * PLANE;  // uniform base per plane
#pragma unroll
      for (int c = 0; c < 4; ++c) s[p * 4 + c] = bp[off4[c]];
    }
  };
  // in-register transpose -> 4x ds_write_b128 (lane = entry, 16B of 4 planes)
  auto stw = [&](const float (&s)[16]) {
#pragma unroll
    for (int c = 0; c < 4; ++c)
      halo[wv][eclamp[c]] = make_float4(s[0 * 4 + c], s[1 * 4 + c],
                                        s[2 * 4 + c], s[3 * 4 + c]);
  };

  // ---------------- phase 1: per-wave partial correlation ------------------
  float acc[K2];
#pragma unroll
  for (int k = 0; k < K2; ++k) acc[k] = 0.f;

  auto corr = [&]() {
    const float4 c4 = halo[wv][(ty + PD) * HW_ + (tx + PD)];
#pragma unroll
    for (int di = 0; di < KK; ++di)
#pragma unroll
      for (int dj = 0; dj < KK; ++dj) {
        const float4 n4 = halo[wv][(ty + di) * HW_ + (tx + dj)];
        acc[di * KK + dj] += c4.x * n4.x + c4.y * n4.y + c4.z * n4.z + c4.w * n4.w;
      }
  };

  {
    float sA[16], sB[16];
    ldg(xw + 0 * GSTRIDE, sA);
    ldg(xw + 1 * GSTRIDE, sB);
    stw(sA); ldg(xw + 2 * GSTRIDE, sA); corr();   // g=0
    stw(sB); ldg(xw + 3 * GSTRIDE, sB); corr();   // g=1
    stw(sA); corr();                              // g=2
    stw(sB); corr();                              // g=3
  }

  // zero OOB taps (zero-padding semantics), cross-wave reduce in LDS
#pragma unroll
  for (int di = 0; di < KK; ++di)
#pragma unroll
    for (int dj = 0; dj < KK; ++dj) {
      const int hh = h + di - PD, ww = w + dj - PD;
      if ((unsigned)hh >= (unsigned)HT || (unsigned)ww >= (unsigned)WD)
        acc[di * KK + dj] = 0.f;
    }
#pragma unroll
  for (int k = 0; k < K2; ++k) atomicAdd(&wred[lane][k], acc[k]);

  __syncthreads();

  // ---------------- normalize (feat prologue issued first) -----------------
  float sA[16], sB[16];
  ldg(fw + 0 * GSTRIDE, sA);
  ldg(fw + 1 * GSTRIDE, sB);

  float wk[K2];
  float ssum = 0.f;
#pragma unroll
  for (int k = 0; k < K2; ++k) { wk[k] = wred[lane][k]; ssum += wk[k]; }
  const float invs = 1.0f / ssum;
#pragma unroll
  for (int k = 0; k < K2; ++k) wk[k] *= invs;
  if (wv == 0) inv[lane] = invs;

  // ---------------- phase 2: per-wave aggregation over feat ----------------
  float4 ov[GPW];
#pragma unroll
  for (int g = 0; g < GPW; ++g) ov[g] = make_float4(0.f, 0.f, 0.f, 0.f);

  auto agg = [&](float4& o) {
#pragma unroll
    for (int di = 0; di < KK; ++di)
#pragma unroll
      for (int dj = 0; dj < KK; ++dj) {
        const float4 n4 = halo[wv][(ty + di) * HW_ + (tx + dj)];
        const float f = wk[di * KK + dj];
        o.x += f * n4.x; o.y += f * n4.y; o.z += f * n4.z; o.w += f * n4.w;
      }
  };

  stw(sA); ldg(fw + 2 * GSTRIDE, sA); agg(ov[0]);
  stw(sB); ldg(fw + 3 * GSTRIDE, sB); agg(ov[1]);
  stw(sA); agg(ov[2]);
  stw(sB); agg(ov[3]);

  const size_t ob = (size_t)n * CC * PLANE + (size_t)wv * 16 * PLANE +
                    (size_t)(h * WD + w);
#pragma unroll
  for (int g = 0; g < GPW; ++g) {
    out[ob + (size_t)(4 * g + 0) * PLANE] = ov[g].x;
    out[ob + (size_t)(4 * g + 1) * PLANE] = ov[g].y;
    out[ob + (size_t)(4 * g + 2) * PLANE] = ov[g].z;
    out[ob + (size_t)(4 * g + 3) * PLANE] = ov[g].w;
  }

  __syncthreads();  // wred/inv stable for the cooperative pairwise store

  // ---- pairwise_weight (n,h,w,k): 784 contiguous floats per tile row ------
#pragma unroll
  for (int r = 0; r < TH; ++r) {
    float* seg = pw + (size_t)(n * PLANE + (by * TH + r) * WD + bx * TW) * K2;
    {
      const int idx = tid;  // 512 threads: one full chunk + remainder
      const int col = idx / K2, k = idx - col * K2;
      seg[idx] = wred[r * TW + col][k] * inv[r * TW + col];
    }
    const int idx2 = 512 + tid;
    if (idx2 < TW * K2) {
      const int col = idx2 / K2, k = idx2 - col * K2;
      seg[idx2] = wred[r * TW + col][k] * inv[r * TW + col];
    }
  }
}

}  // namespace

extern "C" void kernel_launch(void* const* d_in, const int* in_sizes, int n_in,
                              void* d_out, int out_size, void* d_ws, size_t ws_size,
                              hipStream_t stream) {
  const float* x    = (const float*)d_in[0];
  const float* feat = (const float*)d_in[1];
  float* out        = (float*)d_out;
  dim3 grid(WD / TW, HT / TH, CN);  // (5, 20, 4) = 400 blocks x 512 threads
  lnl2d_v4<<<grid, 512, 0, stream>>>(x, feat, out);
}

// Round 6
// 172.211 us; speedup vs baseline: 1.0010x; 1.0010x over previous
//
#include <hip/hip_runtime.h>

// LocalNonLocal2D v5: fused, 8 waves/block, reg-staged halo, DOUBLE-buffered.
//   Wave wv owns channels [16wv,16wv+16): 4 groups of 4 channels.
//   Staging per group: 4x global float4 loads (lane = one (row,col-chunk) of a
//   10x24 halo grid, 16B-aligned, chunk-granular clamped), in-register
//   transpose, 4x ds_write_b128 into a [10][25]-float4 halo (bank-spread).
//   Schedule per iter: corr(B_cur); stw(B_next); ldg(s_next <- g+2):
//   every stw(Bx) is separated from corr(Bx) by a full other-buffer corr, so
//   the in-order per-wave LDS queue never exposes write latency (v4's bug).
//   Cross-wave w[49] reduce via LDS atomics into wred[64][53].

namespace {

constexpr int CN = 4, CC = 128, HT = 80, WD = 80;
constexpr int KK = 7, K2 = 49, PD = 3;
constexpr int TW = 16, TH = 4;       // pixel tile (64 px, lane = pixel)
constexpr int HROWS = 10, HCH = 6;   // halo grid: 10 rows x 6 chunks (24 cols)
constexpr int HROW = 25;             // float4 row stride (25: bank spread)
constexpr int HENT = HROWS * HROW;   // 250 float4 entries per buffer
constexpr int PLANE = HT * WD;       // 6400
constexpr int GSTRIDE = 4 * PLANE;   // one 4-channel group step
constexpr int OUT_ELEMS = CN * CC * PLANE;
constexpr int NW = 8, GPW = 4;       // 8 waves x 16 ch
constexpr int WR = 53;               // wred row stride

__global__ __launch_bounds__(512) void lnl2d_v5(const float* __restrict__ x,
                                                const float* __restrict__ feat,
                                                float* __restrict__ dout) {
  __shared__ float4 halo[NW][2][HENT];  // 64000 B
  __shared__ float wred[64][WR];        // 13568 B
  __shared__ float inv[64];             // 256 B   -> 77.8 KB, 2 blocks/CU

  const int tid  = (int)threadIdx.x;
  const int wv   = tid >> 6;
  const int lane = tid & 63;
  const int tx = lane & (TW - 1), ty = lane >> 4;
  const int bx = (int)blockIdx.x, by = (int)blockIdx.y, n = (int)blockIdx.z;
  const int h = by * TH + ty, w = bx * TW + tx;

  const float* xw = x + (size_t)n * CC * PLANE + (size_t)wv * 16 * PLANE;
  const float* fw = feat + (size_t)n * CC * PLANE + (size_t)wv * 16 * PLANE;
  float* out = dout;
  float* pw  = dout + OUT_ELEMS;

  // lane -> one (row, col-chunk) of the halo grid; grid col 0 = image col
  // x0-4 so all chunks are 16B-aligned. Chunk-granular clamp: a clamped
  // chunk's true cols are entirely OOB -> garbage is zeroed via OOB taps.
  const int m  = lane < HROWS * HCH ? lane : HROWS * HCH - 1;  // 60 active
  const int hr = m / HCH, hc = m - hr * HCH;
  int gh = by * TH - PD + hr;
  gh = gh < 0 ? 0 : (gh > HT - 1 ? HT - 1 : gh);
  int gwc = bx * TW - 4 + 4 * hc;
  gwc = gwc < 0 ? 0 : (gwc > WD - 4 ? WD - 4 : gwc);
  const int goffpx = gh * WD + gwc;       // 16B-aligned float4 offset
  const int ebase  = hr * HROW + hc * 4;  // 4 consecutive halo entries

  auto ldg = [&](const float* gbase, float4 (&s)[4]) {
#pragma unroll
    for (int p = 0; p < 4; ++p)
      s[p] = *(const float4*)(gbase + p * PLANE + goffpx);
  };
  auto stw = [&](int buf, const float4 (&s)[4]) {
#pragma unroll
    for (int j = 0; j < 4; ++j)
      halo[wv][buf][ebase + j] =
          make_float4(((const float*)&s[0])[j], ((const float*)&s[1])[j],
                      ((const float*)&s[2])[j], ((const float*)&s[3])[j]);
  };

  // init wred; barrier before any atomics land
#pragma unroll
  for (int i = 0; i < (64 * WR + 511) / 512; ++i) {
    const int idx = i * 512 + tid;
    if (idx < 64 * WR) ((float*)wred)[idx] = 0.f;
  }
  __syncthreads();

  // ---------------- phase 1: per-wave partial correlation ------------------
  float acc[K2];
#pragma unroll
  for (int k = 0; k < K2; ++k) acc[k] = 0.f;

  auto corr = [&](int buf) {
    const float4* hb = halo[wv][buf];
    const float4 c4 = hb[(ty + PD) * HROW + tx + PD + 1];
#pragma unroll
    for (int di = 0; di < KK; ++di)
#pragma unroll
      for (int dj = 0; dj < KK; ++dj) {
        const float4 n4 = hb[(ty + di) * HROW + tx + dj + 1];
        acc[di * KK + dj] += c4.x * n4.x + c4.y * n4.y + c4.z * n4.z + c4.w * n4.w;
      }
  };

  float4 sA[4], sB[4];
  ldg(xw + 0 * GSTRIDE, sA);
  ldg(xw + 1 * GSTRIDE, sB);
  stw(0, sA); ldg(xw + 2 * GSTRIDE, sA);
  corr(0); stw(1, sB); ldg(xw + 3 * GSTRIDE, sB);   // g0
  corr(1); stw(0, sA); ldg(fw + 0 * GSTRIDE, sA);   // g1 (+feat prefetch)
  corr(0); stw(1, sB); ldg(fw + 1 * GSTRIDE, sB);   // g2
  corr(1);                                          // g3

  // zero OOB taps (zero-padding semantics), cross-wave reduce in LDS
#pragma unroll
  for (int di = 0; di < KK; ++di)
#pragma unroll
    for (int dj = 0; dj < KK; ++dj) {
      const int hh = h + di - PD, ww = w + dj - PD;
      if ((unsigned)hh >= (unsigned)HT || (unsigned)ww >= (unsigned)WD)
        acc[di * KK + dj] = 0.f;
    }
#pragma unroll
  for (int k = 0; k < K2; ++k) atomicAdd(&wred[lane][k], acc[k]);

  __syncthreads();  // register prefetch loads (sA,sB) stay in flight

  // ---------------- normalize (feat f0,f1 already in flight) ---------------
  float wk[K2];
  float ssum = 0.f;
#pragma unroll
  for (int k = 0; k < K2; ++k) { wk[k] = wred[lane][k]; ssum += wk[k]; }
  const float invs = 1.0f / ssum;
#pragma unroll
  for (int k = 0; k < K2; ++k) wk[k] *= invs;
  if (wv == 0) inv[lane] = invs;

  // ---------------- phase 2: per-wave aggregation over feat ----------------
  float4 ov[GPW];
#pragma unroll
  for (int g = 0; g < GPW; ++g) ov[g] = make_float4(0.f, 0.f, 0.f, 0.f);

  auto agg = [&](int buf, float4& o) {
    const float4* hb = halo[wv][buf];
#pragma unroll
    for (int di = 0; di < KK; ++di)
#pragma unroll
      for (int dj = 0; dj < KK; ++dj) {
        const float4 n4 = hb[(ty + di) * HROW + tx + dj + 1];
        const float f = wk[di * KK + dj];
        o.x += f * n4.x; o.y += f * n4.y; o.z += f * n4.z; o.w += f * n4.w;
      }
  };

  stw(0, sA); ldg(fw + 2 * GSTRIDE, sA);
  agg(0, ov[0]); stw(1, sB); ldg(fw + 3 * GSTRIDE, sB);  // f0
  agg(1, ov[1]); stw(0, sA);                              // f1
  agg(0, ov[2]); stw(1, sB);                              // f2
  agg(1, ov[3]);                                          // f3

  const size_t ob = (size_t)n * CC * PLANE + (size_t)wv * 16 * PLANE +
                    (size_t)(h * WD + w);
#pragma unroll
  for (int g = 0; g < GPW; ++g) {
    out[ob + (size_t)(4 * g + 0) * PLANE] = ov[g].x;
    out[ob + (size_t)(4 * g + 1) * PLANE] = ov[g].y;
    out[ob + (size_t)(4 * g + 2) * PLANE] = ov[g].z;
    out[ob + (size_t)(4 * g + 3) * PLANE] = ov[g].w;
  }

  __syncthreads();  // wred/inv stable for the cooperative pairwise store

  // ---- pairwise_weight (n,h,w,k): 784 contiguous floats per tile row ------
#pragma unroll
  for (int r = 0; r < TH; ++r) {
    float* seg = pw + (size_t)(n * PLANE + (by * TH + r) * WD + bx * TW) * K2;
    {
      const int idx = tid;
      const int col = idx / K2, k = idx - col * K2;
      seg[idx] = wred[r * TW + col][k] * inv[r * TW + col];
    }
    const int idx2 = 512 + tid;
    if (idx2 < TW * K2) {
      const int col = idx2 / K2, k = idx2 - col * K2;
      seg[idx2] = wred[r * TW + col][k] * inv[r * TW + col];
    }
  }
}

}  // namespace

extern "C" void kernel_launch(void* const* d_in, const int* in_sizes, int n_in,
                              void* d_out, int out_size, void* d_ws, size_t ws_size,
                              hipStream_t stream) {
  const float* x    = (const float*)d_in[0];
  const float* feat = (const float*)d_in[1];
  float* out        = (float*)d_out;
  dim3 grid(WD / TW, HT / TH, CN);  // (5, 20, 4) = 400 blocks x 512 threads
  lnl2d_v5<<<grid, 512, 0, stream>>>(x, feat, out);
}

// Round 7
// 137.663 us; speedup vs baseline: 1.2522x; 1.2510x over previous
//
#include <hip/hip_runtime.h>

// LocalNonLocal2D v6 = v3 (best, 74us) + stride-23 halo pad + depth-3 prefetch.
//   4 waves/block, wave owns channels [32wv,32wv+32) = 8 groups of 4ch.
//   Halo: 10 rows x 23 float4 (stride 23 = odd -> conflict-free b128 reads),
//   staged via global_load_lds gather (15 chunks of 64 floats), ring of 4
//   buffers, 3 groups in flight, counted s_waitcnt vmcnt(45/30/15/0).
//   Pad entries (col 22, tail chunk) are loaded (clamped addr) never read.
//   Cross-wave w[49] reduce via LDS atomics into wred[64][53].

namespace {

constexpr int CN = 4, CC = 128, HT = 80, WD = 80;
constexpr int KK = 7, K2 = 49, PD = 3;
constexpr int TW = 16, TH = 4;            // pixel tile (64 px, lane = pixel)
constexpr int HROW = 23;                  // halo row stride in float4 (padded)
constexpr int HENT = 10 * HROW;           // 230 float4 entries
constexpr int HCHUNK = (HENT * 4 + 63) / 64;  // 15 chunks of 64 floats
constexpr int HPADF = HCHUNK * 64;        // 960 floats per buffer
constexpr int PLANE = HT * WD;            // 6400
constexpr int GSTRIDE = 4 * PLANE;        // one 4-channel group step
constexpr int OUT_ELEMS = CN * CC * PLANE;
constexpr int NW = 4, GPW = 8;            // 4 waves x 32 ch (8 groups of 4)
constexpr int WR = 53;                    // wred row stride (odd)

__device__ __forceinline__ void make_off(int* off, int bx, int by, int lane) {
#pragma unroll
  for (int q = 0; q < HCHUNK; ++q) {
    int f = q * 64 + lane;
    int e = f >> 2;
    if (e > HENT - 1) e = HENT - 1;   // tail-pad lanes re-load last entry
    const int ch = f & 3;
    const int r  = e / HROW;
    const int cl = e - r * HROW;      // 0..22; col 22 = row pad, never read
    int gh = by * TH - PD + r;
    gh = gh < 0 ? 0 : (gh > HT - 1 ? HT - 1 : gh);
    int gw = bx * TW - PD + cl;
    gw = gw < 0 ? 0 : (gw > WD - 1 ? WD - 1 : gw);
    off[q] = ch * PLANE + gh * WD + gw;  // clamped; OOB taps zeroed later
  }
}

__device__ __forceinline__ void issue_chunks(const float* gbase, const int* off,
                                             float* lds) {
#if __has_builtin(__builtin_amdgcn_global_load_lds)
#pragma unroll
  for (int q = 0; q < HCHUNK; ++q) {
    __builtin_amdgcn_global_load_lds(
        (const __attribute__((address_space(1))) void*)(gbase + off[q]),
        (__attribute__((address_space(3))) void*)(lds + q * 64), 4, 0, 0);
  }
#else
  const int lane = (int)(threadIdx.x & 63);
#pragma unroll
  for (int q = 0; q < HCHUNK; ++q) lds[q * 64 + lane] = gbase[off[q]];
  asm volatile("s_waitcnt lgkmcnt(0)" ::: "memory");
#endif
}

#define WAIT_VM(n_lit)                                      \
  asm volatile("s_waitcnt vmcnt(" #n_lit ")" ::: "memory"); \
  __builtin_amdgcn_sched_barrier(0)

__global__ __launch_bounds__(256) void lnl2d_v6(const float* __restrict__ x,
                                                const float* __restrict__ feat,
                                                float* __restrict__ dout) {
  __shared__ float halo[NW * 4][HPADF];   // 61440 B (ring of 4 per wave)
  __shared__ float wred[64][WR];          // 13568 B
  __shared__ float inv[64];               // 256 B -> 75.3 KB, 2 blocks/CU

  const int tid  = (int)threadIdx.x;
  const int wv   = tid >> 6;
  const int lane = tid & 63;
  const int tx = lane & (TW - 1), ty = lane >> 4;
  const int bx = (int)blockIdx.x, by = (int)blockIdx.y, n = (int)blockIdx.z;
  const int h = by * TH + ty, w = bx * TW + tx;

  const float* xw = x + (size_t)n * CC * PLANE + (size_t)wv * 32 * PLANE;
  const float* fw = feat + (size_t)n * CC * PLANE + (size_t)wv * 32 * PLANE;
  float* out = dout;
  float* pw  = dout + OUT_ELEMS;

  int off[HCHUNK];
  make_off(off, bx, by, lane);

  // init wred; barrier before any atomics land (vmcnt==0 here: free drain)
#pragma unroll
  for (int i = 0; i < (64 * WR + 255) / 256; ++i) {
    const int idx = i * 256 + tid;
    if (idx < 64 * WR) ((float*)wred)[idx] = 0.f;
  }
  __syncthreads();

  float* hb[4] = {halo[wv * 4 + 0], halo[wv * 4 + 1], halo[wv * 4 + 2],
                  halo[wv * 4 + 3]};

  // ---------------- phase 1: per-wave partial correlation ------------------
  float acc[K2];
#pragma unroll
  for (int k = 0; k < K2; ++k) acc[k] = 0.f;

  auto corr = [&](const float* b) {
    const float4* h4 = (const float4*)b;
    const float4 c4 = h4[(ty + PD) * HROW + tx + PD];
#pragma unroll
    for (int di = 0; di < KK; ++di)
#pragma unroll
      for (int dj = 0; dj < KK; ++dj) {
        const float4 n4 = h4[(ty + di) * HROW + tx + dj];
        acc[di * KK + dj] += c4.x * n4.x + c4.y * n4.y + c4.z * n4.z + c4.w * n4.w;
      }
  };

  issue_chunks(xw + 0 * GSTRIDE, off, hb[0]);
  issue_chunks(xw + 1 * GSTRIDE, off, hb[1]);
  issue_chunks(xw + 2 * GSTRIDE, off, hb[2]);
#pragma unroll
  for (int g = 0; g < GPW; ++g) {
    if (g < GPW - 3) issue_chunks(xw + (g + 3) * GSTRIDE, off, hb[(g + 3) & 3]);
    if (g < GPW - 3)      { WAIT_VM(45); }
    else if (g == GPW - 3){ WAIT_VM(30); }
    else if (g == GPW - 2){ WAIT_VM(15); }
    else                  { WAIT_VM(0); }
    corr(hb[g & 3]);
  }

  // zero OOB taps (zero-padding semantics), cross-wave reduce in LDS
#pragma unroll
  for (int di = 0; di < KK; ++di)
#pragma unroll
    for (int dj = 0; dj < KK; ++dj) {
      const int hh = h + di - PD, ww = w + dj - PD;
      if ((unsigned)hh >= (unsigned)HT || (unsigned)ww >= (unsigned)WD)
        acc[di * KK + dj] = 0.f;
    }
#pragma unroll
  for (int k = 0; k < K2; ++k) atomicAdd(&wred[lane][k], acc[k]);

  __syncthreads();  // vmcnt==0 here (phase 1 drained): free barrier

  // ---- feat prologue first, normalize math under its latency --------------
  issue_chunks(fw + 0 * GSTRIDE, off, hb[0]);
  issue_chunks(fw + 1 * GSTRIDE, off, hb[1]);
  issue_chunks(fw + 2 * GSTRIDE, off, hb[2]);

  float wk[K2];
  float ssum = 0.f;
#pragma unroll
  for (int k = 0; k < K2; ++k) { wk[k] = wred[lane][k]; ssum += wk[k]; }
  const float invs = 1.0f / ssum;
#pragma unroll
  for (int k = 0; k < K2; ++k) wk[k] *= invs;
  if (wv == 0) inv[lane] = invs;

  // ---------------- phase 2: per-wave aggregation over feat ----------------
  float4 ov[GPW];
#pragma unroll
  for (int g = 0; g < GPW; ++g) ov[g] = make_float4(0.f, 0.f, 0.f, 0.f);

#pragma unroll
  for (int g = 0; g < GPW; ++g) {
    if (g < GPW - 3) issue_chunks(fw + (g + 3) * GSTRIDE, off, hb[(g + 3) & 3]);
    if (g < GPW - 3)      { WAIT_VM(45); }
    else if (g == GPW - 3){ WAIT_VM(30); }
    else if (g == GPW - 2){ WAIT_VM(15); }
    else                  { WAIT_VM(0); }
    const float4* h4 = (const float4*)hb[g & 3];
#pragma unroll
    for (int di = 0; di < KK; ++di)
#pragma unroll
      for (int dj = 0; dj < KK; ++dj) {
        const float4 n4 = h4[(ty + di) * HROW + tx + dj];
        const float f = wk[di * KK + dj];
        ov[g].x += f * n4.x; ov[g].y += f * n4.y; ov[g].z += f * n4.z; ov[g].w += f * n4.w;
      }
  }

  const size_t ob = (size_t)n * CC * PLANE + (size_t)wv * 32 * PLANE +
                    (size_t)(h * WD + w);
#pragma unroll
  for (int g = 0; g < GPW; ++g) {
    out[ob + (size_t)(4 * g + 0) * PLANE] = ov[g].x;
    out[ob + (size_t)(4 * g + 1) * PLANE] = ov[g].y;
    out[ob + (size_t)(4 * g + 2) * PLANE] = ov[g].z;
    out[ob + (size_t)(4 * g + 3) * PLANE] = ov[g].w;
  }

  __syncthreads();  // wred/inv stable for the cooperative pairwise store

  // ---- pairwise_weight (n,h,w,k): 784 contiguous floats per tile row ------
#pragma unroll
  for (int r = 0; r < TH; ++r) {
    float* seg = pw + (size_t)(n * PLANE + (by * TH + r) * WD + bx * TW) * K2;
#pragma unroll
    for (int i = 0; i < (TW * K2) / 256; ++i) {  // 3 full chunks of 256
      const int idx = i * 256 + tid;
      const int col = idx / K2, k = idx - col * K2;
      seg[idx] = wred[r * TW + col][k] * inv[r * TW + col];
    }
    const int rem = TW * K2 - 256 * ((TW * K2) / 256);  // 16
    if (tid < rem) {
      const int idx = 256 * ((TW * K2) / 256) + tid;
      const int col = idx / K2, k = idx - col * K2;
      seg[idx] = wred[r * TW + col][k] * inv[r * TW + col];
    }
  }
}

}  // namespace

extern "C" void kernel_launch(void* const* d_in, const int* in_sizes, int n_in,
                              void* d_out, int out_size, void* d_ws, size_t ws_size,
                              hipStream_t stream) {
  const float* x    = (const float*)d_in[0];
  const float* feat = (const float*)d_in[1];
  float* out        = (float*)d_out;
  dim3 grid(WD / TW, HT / TH, CN);  // (5, 20, 4) = 400 blocks x 256 threads
  lnl2d_v6<<<grid, 256, 0, stream>>>(x, feat, out);
}